// Round 1
// 214.863 us; speedup vs baseline: 1.0475x; 1.0475x over previous
//
#include <hip/hip_runtime.h>
#include <hip/hip_bf16.h>

// ---------- types ----------
typedef short bf16x8 __attribute__((ext_vector_type(8)));
typedef float f32x4 __attribute__((ext_vector_type(4)));

typedef __attribute__((address_space(3))) unsigned int lds_u32;
typedef __attribute__((address_space(1))) const unsigned int gbl_cu32;

__device__ __forceinline__ void async_ld16(void* lds, const void* g) {
  __builtin_amdgcn_global_load_lds((gbl_cu32*)g, (lds_u32*)lds, 16, 0, 0);
}

__device__ __forceinline__ unsigned short f2bf(float f) {
  unsigned u = __builtin_bit_cast(unsigned, f);
  u += 0x7FFFu + ((u >> 16) & 1u);   // RNE; inputs finite
  return (unsigned short)(u >> 16);
}

// ---------- prep (merged): x->bf16, mask(qkv_w), mask(proj_w) ----------
__global__ void k_prep(const float* __restrict__ x, unsigned short* __restrict__ xo,
                       const float* __restrict__ w1, const float* __restrict__ m1,
                       unsigned short* __restrict__ o1,
                       const float* __restrict__ w2, const float* __restrict__ m2,
                       unsigned short* __restrict__ o2) {
  int blk = blockIdx.x;
  if (blk < 6144) {
    int i = blk * 256 + threadIdx.x;
    float4 v = ((const float4*)x)[i];
    ushort4 r;
    r.x = f2bf(v.x); r.y = f2bf(v.y); r.z = f2bf(v.z); r.w = f2bf(v.w);
    ((ushort4*)xo)[i] = r;
  } else if (blk < 6144 + 1728) {
    int i = (blk - 6144) * 256 + threadIdx.x;
    float4 wv = ((const float4*)w1)[i];
    float4 mv = ((const float4*)m1)[i];
    ushort4 r;
    r.x = f2bf(mv.x >= 0.005f ? wv.x : 0.0f);
    r.y = f2bf(mv.y >= 0.005f ? wv.y : 0.0f);
    r.z = f2bf(mv.z >= 0.005f ? wv.z : 0.0f);
    r.w = f2bf(mv.w >= 0.005f ? wv.w : 0.0f);
    ((ushort4*)o1)[i] = r;
  } else {
    int i = (blk - 6144 - 1728) * 256 + threadIdx.x;
    float4 wv = ((const float4*)w2)[i];
    float4 mv = ((const float4*)m2)[i];
    ushort4 r;
    r.x = f2bf(mv.x >= 0.005f ? wv.x : 0.0f);
    r.y = f2bf(mv.y >= 0.005f ? wv.y : 0.0f);
    r.z = f2bf(mv.z >= 0.005f ? wv.z : 0.0f);
    r.w = f2bf(mv.w >= 0.005f ? wv.w : 0.0f);
    ((ushort4*)o2)[i] = r;
  }
}

// ---------- GEMM: C[M,N] = A[M,K] * B[N,K]^T + bias[N] ----------
// 128x128 tile, BK=64, 4 waves (2x2), 16x16x32 bf16 MFMA. LDS XOR-swizzled:
// 16B chunk c of row stored at slot c ^ (row&7); staging permutes the *global*
// source per lane (same 128B row span -> still coalesced; lds-dma dest stays
// base+lane*16). (unchanged this round)
template <bool OUT_BF16>
__global__ __launch_bounds__(256) void k_gemm_bt(
    const unsigned short* __restrict__ A,
    const unsigned short* __restrict__ Bw,
    const float* __restrict__ bias,
    void* __restrict__ Cout,
    int M, int Nn, int K)
{
  __shared__ unsigned short As[128 * 64];   // 16 KB, rows of 128 B = 8 chunks
  __shared__ unsigned short Bs[128 * 64];
  const int tid = threadIdx.x, lane = tid & 63;
  const int wv = tid >> 6, wr = wv >> 1, wc = wv & 1;
  const int q4 = lane >> 4, r = lane & 15;
  const long bm = (long)blockIdx.x * 128, bn = (long)blockIdx.y * 128;

  f32x4 acc[4][4] = {};

  int srow[4], sco[4];
#pragma unroll
  for (int j = 0; j < 4; ++j) {
    const int s = j * 256 + tid;
    srow[j] = s >> 3;
    sco[j] = ((s & 7) ^ (srow[j] & 7)) * 16;  // byte offset within row
  }

  for (int k0 = 0; k0 < K; k0 += 64) {
    __syncthreads();
#pragma unroll
    for (int j = 0; j < 4; ++j) {
      const int ldsoff = j * 4096 + tid * 16;
      async_ld16((char*)As + ldsoff,
                 (const char*)(A + (bm + srow[j]) * (long)K + k0) + sco[j]);
      async_ld16((char*)Bs + ldsoff,
                 (const char*)(Bw + (bn + srow[j]) * (long)K + k0) + sco[j]);
    }
    __syncthreads();

#pragma unroll
    for (int ks = 0; ks < 2; ++ks) {
      bf16x8 af[4], bfr[4];
#pragma unroll
      for (int i = 0; i < 4; ++i) {
        const int row = wr * 64 + i * 16 + r;
        const int ch = (ks * 4 + q4) ^ (row & 7);
        af[i] = *(const bf16x8*)(As + row * 64 + ch * 8);
      }
#pragma unroll
      for (int j = 0; j < 4; ++j) {
        const int row = wc * 64 + j * 16 + r;
        const int ch = (ks * 4 + q4) ^ (row & 7);
        bfr[j] = *(const bf16x8*)(Bs + row * 64 + ch * 8);
      }
#pragma unroll
      for (int i = 0; i < 4; ++i)
#pragma unroll
        for (int j = 0; j < 4; ++j)
          acc[i][j] = __builtin_amdgcn_mfma_f32_16x16x32_bf16(af[i], bfr[j], acc[i][j], 0, 0, 0);
    }
  }

#pragma unroll
  for (int j = 0; j < 4; ++j) {
    const long col = bn + wc * 64 + j * 16 + r;
    const float bv = bias[col];
#pragma unroll
    for (int i = 0; i < 4; ++i) {
#pragma unroll
      for (int rr = 0; rr < 4; ++rr) {
        const long rowg = bm + wr * 64 + i * 16 + q4 * 4 + rr;
        const float v = acc[i][j][rr] + bv;
        if (OUT_BF16)
          ((unsigned short*)Cout)[rowg * Nn + col] = f2bf(v);
        else
          ((float*)Cout)[rowg * Nn + col] = v;
      }
    }
  }
}

// ---------- transpose V: qkv[b,n,2C + h*64 + d] -> vt[(bh*64+d)*1024 + n] ----------
__global__ __launch_bounds__(256) void k_transpose_v(const unsigned short* __restrict__ qkv,
                                                     unsigned short* __restrict__ vt) {
  __shared__ unsigned short T[64][72];
  const int tid = threadIdx.x;
  const int bh = blockIdx.y, b = bh / 12, h = bh % 12;
  const int n0 = blockIdx.x * 64;
#pragma unroll
  for (int i = 0; i < 2; ++i) {
    int c = tid + i * 256, row = c >> 3, ch = c & 7;
    uint4 v = *(const uint4*)(qkv + ((long)(b * 1024 + n0 + row)) * 2304 + 1536 + h * 64 + ch * 8);
    *(uint4*)(&T[row][ch * 8]) = v;
  }
  __syncthreads();
#pragma unroll
  for (int i = 0; i < 2; ++i) {
    int c = tid + i * 256, d = c >> 3, ch = c & 7;
    unsigned short tmp[8];
#pragma unroll
    for (int j = 0; j < 8; ++j) tmp[j] = T[ch * 8 + j][d];
    *(uint4*)(vt + ((long)bh * 64 + d) * 1024 + n0 + ch * 8) = *(const uint4*)tmp;
  }
}

// ---------- flash attention (v3: async double-buffered K/V staging) ----------
// Change vs v2: K/V tiles staged via global_load_lds into 2 LDS buffers,
// issued one tile ahead, ONE barrier per tile (was: sync reg-staging with
// 2 barriers exposing full global latency each tile). LDS rows are linear
// 128B with the same XOR chunk-swizzle as k_gemm_bt (lds-dma needs linear
// dest; swizzle applied to global source + read index — both-sides rule).
// Read-side bank check: lanes r and r+8 alias (2-way) = free.
__global__ __launch_bounds__(256) void k_flash(
    const unsigned short* __restrict__ qkv,  // [8192, 2304]
    const unsigned short* __restrict__ vt,   // [96*64, 1024]
    unsigned short* __restrict__ outp)       // [8192, 768]
{
  constexpr int LDP = 72;                     // Ps keeps +pad (reg-written)
  __shared__ unsigned short Ks[2][64 * 64];   // 8 KB per buf, linear swizzled
  __shared__ unsigned short Vts[2][64 * 64];
  __shared__ unsigned short Ps[4 * 32 * LDP];

  const int tid = threadIdx.x, lane = tid & 63;
  const int wv = tid >> 6, q4 = lane >> 4, r = lane & 15;
  const int bh = blockIdx.y, b = bh / 12, h = bh % 12;
  const int q0 = blockIdx.x * 128;
  const long qrow0 = (long)b * 1024;

  // swizzled staging offsets: slot s = i*256+tid, row = s>>3, chunk = (s&7)^(row&7)
  int srow[2], sco[2];
#pragma unroll
  for (int i = 0; i < 2; ++i) {
    const int s = i * 256 + tid;
    srow[i] = s >> 3;
    sco[i] = ((s & 7) ^ (srow[i] & 7)) * 8;   // element offset within 64-elem row
  }

  const unsigned short* Kg = qkv + qrow0 * 2304 + 768 + (long)h * 64;  // K rows
  const unsigned short* Vg = vt + (long)bh * 64 * 1024;                // V^T rows

  // Q fragments (held in regs for whole kernel)
  bf16x8 aq[2][2];
#pragma unroll
  for (int i = 0; i < 2; ++i)
#pragma unroll
    for (int kc = 0; kc < 2; ++kc)
      aq[i][kc] = *(const bf16x8*)(qkv + (qrow0 + q0 + wv * 32 + i * 16 + r) * 2304 + h * 64 + kc * 32 + q4 * 8);

  f32x4 o[2][4] = {};
  f32x4 lsum[2] = {};
  const bf16x8 ones = {0x3F80, 0x3F80, 0x3F80, 0x3F80, 0x3F80, 0x3F80, 0x3F80, 0x3F80};

  // stage tile (n0 = kv row offset) into buffer `buf`
  auto stage = [&](int n0, int buf) {
#pragma unroll
    for (int i = 0; i < 2; ++i) {
      const int ldsoff = (i * 256 + tid) * 16;  // linear dest: base + lane*16
      async_ld16((char*)Ks[buf] + ldsoff,
                 (const void*)(Kg + (long)(n0 + srow[i]) * 2304 + sco[i]));
      async_ld16((char*)Vts[buf] + ldsoff,
                 (const void*)(Vg + (long)srow[i] * 1024 + n0 + sco[i]));
    }
  };

  stage(0, 0);  // prologue prefetch

  for (int kt = 0; kt < 16; ++kt) {
    const int cur = kt & 1;
    // barrier drains this wave's lds-dma (stage(kt), issued a full compute
    // phase ago) and guarantees all waves finished reading buf cur^1.
    __syncthreads();
    if (kt < 15) stage((kt + 1) * 64, cur ^ 1);

    const unsigned short* Kc = Ks[cur];
    const unsigned short* Vc = Vts[cur];

    // ---- QK^T ----
    f32x4 s[2][4] = {};
    {
      bf16x8 bk[4][2];
#pragma unroll
      for (int j = 0; j < 4; ++j)
#pragma unroll
        for (int kc = 0; kc < 2; ++kc) {
          const int row = j * 16 + r;
          const int ch = (kc * 4 + q4) ^ (row & 7);
          bk[j][kc] = *(const bf16x8*)(Kc + row * 64 + ch * 8);
        }
#pragma unroll
      for (int i = 0; i < 2; ++i)
#pragma unroll
        for (int j = 0; j < 4; ++j) {
          s[i][j] = __builtin_amdgcn_mfma_f32_16x16x32_bf16(aq[i][0], bk[j][0], s[i][j], 0, 0, 0);
          s[i][j] = __builtin_amdgcn_mfma_f32_16x16x32_bf16(aq[i][1], bk[j][1], s[i][j], 0, 0, 0);
        }
    }

    // ---- softmax (fixed-shift exp; normalization deferred to epilogue) ----
#pragma unroll
    for (int i = 0; i < 2; ++i)
#pragma unroll
      for (int j = 0; j < 4; ++j)
#pragma unroll
        for (int rr = 0; rr < 4; ++rr) {
          float p = __expf(fmaf(s[i][j][rr], 0.125f, -2.0f));
          Ps[(wv * 32 + i * 16 + q4 * 4 + rr) * LDP + j * 16 + r] = f2bf(p);
        }

    // ---- PV (+ row-sum via ones-MFMA) ----
    {
      bf16x8 bv[4][2];
#pragma unroll
      for (int jd = 0; jd < 4; ++jd)
#pragma unroll
        for (int kc = 0; kc < 2; ++kc) {
          const int row = jd * 16 + r;
          const int ch = (kc * 4 + q4) ^ (row & 7);
          bv[jd][kc] = *(const bf16x8*)(Vc + row * 64 + ch * 8);
        }
#pragma unroll
      for (int i = 0; i < 2; ++i) {
        bf16x8 ap0 = *(const bf16x8*)(Ps + (wv * 32 + i * 16 + r) * LDP + 0 + q4 * 8);
        bf16x8 ap1 = *(const bf16x8*)(Ps + (wv * 32 + i * 16 + r) * LDP + 32 + q4 * 8);
        lsum[i] = __builtin_amdgcn_mfma_f32_16x16x32_bf16(ap0, ones, lsum[i], 0, 0, 0);
        lsum[i] = __builtin_amdgcn_mfma_f32_16x16x32_bf16(ap1, ones, lsum[i], 0, 0, 0);
#pragma unroll
        for (int jd = 0; jd < 4; ++jd) {
          o[i][jd] = __builtin_amdgcn_mfma_f32_16x16x32_bf16(ap0, bv[jd][0], o[i][jd], 0, 0, 0);
          o[i][jd] = __builtin_amdgcn_mfma_f32_16x16x32_bf16(ap1, bv[jd][1], o[i][jd], 0, 0, 0);
        }
      }
    }
  }

#pragma unroll
  for (int i = 0; i < 2; ++i)
#pragma unroll
    for (int rr = 0; rr < 4; ++rr) {
      const float inv = 1.0f / lsum[i][rr];
      const long rowg = qrow0 + q0 + wv * 32 + i * 16 + q4 * 4 + rr;
#pragma unroll
      for (int jd = 0; jd < 4; ++jd)
        outp[rowg * 768 + h * 64 + jd * 16 + r] = f2bf(o[i][jd][rr] * inv);
    }
}

// ---------- launcher ----------
extern "C" void kernel_launch(void* const* d_in, const int* in_sizes, int n_in,
                              void* d_out, int out_size, void* d_ws, size_t ws_size,
                              hipStream_t stream) {
  const float* x      = (const float*)d_in[0];
  const float* qkv_w  = (const float*)d_in[1];
  const float* qkv_b  = (const float*)d_in[2];
  const float* proj_w = (const float*)d_in[3];
  const float* proj_b = (const float*)d_in[4];
  const float* mask   = (const float*)d_in[5];
  const float* mask_p = (const float*)d_in[6];

  char* ws = (char*)d_ws;
  unsigned short* qkv   = (unsigned short*)(ws);              // 8192*2304*2
  unsigned short* vt    = (unsigned short*)(ws + 37748736);   // 96*64*1024*2
  unsigned short* xbf   = (unsigned short*)(ws + 50331648);   // 8192*768*2 (reused as attn out)
  unsigned short* wqkv  = (unsigned short*)(ws + 62914560);   // 2304*768*2
  unsigned short* wproj = (unsigned short*)(ws + 66453504);   // 768*768*2

  k_prep<<<8448, 256, 0, stream>>>(x, xbf, qkv_w, mask, wqkv, proj_w, mask_p, wproj);
  k_gemm_bt<true><<<dim3(64, 18), 256, 0, stream>>>(xbf, wqkv, qkv_b, qkv, 8192, 2304, 768);
  k_transpose_v<<<dim3(16, 96), 256, 0, stream>>>(qkv, vt);
  k_flash<<<dim3(8, 96), 256, 0, stream>>>(qkv, vt, xbf);
  k_gemm_bt<false><<<dim3(64, 6), 256, 0, stream>>>(xbf, wproj, proj_b, d_out, 8192, 768, 768);
}

// Round 2
// 209.318 us; speedup vs baseline: 1.0752x; 1.0265x over previous
//
#include <hip/hip_runtime.h>
#include <hip/hip_bf16.h>

// ---------- types ----------
typedef short bf16x8 __attribute__((ext_vector_type(8)));
typedef float f32x4 __attribute__((ext_vector_type(4)));

typedef __attribute__((address_space(3))) unsigned int lds_u32;
typedef __attribute__((address_space(1))) const unsigned int gbl_cu32;

__device__ __forceinline__ void async_ld16(void* lds, const void* g) {
  __builtin_amdgcn_global_load_lds((gbl_cu32*)g, (lds_u32*)lds, 16, 0, 0);
}

__device__ __forceinline__ unsigned short f2bf(float f) {
  unsigned u = __builtin_bit_cast(unsigned, f);
  u += 0x7FFFu + ((u >> 16) & 1u);   // RNE; inputs finite
  return (unsigned short)(u >> 16);
}

// ---------- prep (merged): x->bf16, mask(qkv_w), mask(proj_w) ----------
__global__ void k_prep(const float* __restrict__ x, unsigned short* __restrict__ xo,
                       const float* __restrict__ w1, const float* __restrict__ m1,
                       unsigned short* __restrict__ o1,
                       const float* __restrict__ w2, const float* __restrict__ m2,
                       unsigned short* __restrict__ o2) {
  int blk = blockIdx.x;
  if (blk < 6144) {
    int i = blk * 256 + threadIdx.x;
    float4 v = ((const float4*)x)[i];
    ushort4 r;
    r.x = f2bf(v.x); r.y = f2bf(v.y); r.z = f2bf(v.z); r.w = f2bf(v.w);
    ((ushort4*)xo)[i] = r;
  } else if (blk < 6144 + 1728) {
    int i = (blk - 6144) * 256 + threadIdx.x;
    float4 wv = ((const float4*)w1)[i];
    float4 mv = ((const float4*)m1)[i];
    ushort4 r;
    r.x = f2bf(mv.x >= 0.005f ? wv.x : 0.0f);
    r.y = f2bf(mv.y >= 0.005f ? wv.y : 0.0f);
    r.z = f2bf(mv.z >= 0.005f ? wv.z : 0.0f);
    r.w = f2bf(mv.w >= 0.005f ? wv.w : 0.0f);
    ((ushort4*)o1)[i] = r;
  } else {
    int i = (blk - 6144 - 1728) * 256 + threadIdx.x;
    float4 wv = ((const float4*)w2)[i];
    float4 mv = ((const float4*)m2)[i];
    ushort4 r;
    r.x = f2bf(mv.x >= 0.005f ? wv.x : 0.0f);
    r.y = f2bf(mv.y >= 0.005f ? wv.y : 0.0f);
    r.z = f2bf(mv.z >= 0.005f ? wv.z : 0.0f);
    r.w = f2bf(mv.w >= 0.005f ? wv.w : 0.0f);
    ((ushort4*)o2)[i] = r;
  }
}

// ---------- GEMM: C[M,N] = A[M,K] * B[N,K]^T + bias[N] ----------
// v2: double-buffered LDS + ONE barrier per K-step + prefetch issued one
// full compute phase ahead (same transformation that won on k_flash).
// Old structure exposed full global latency at every K-step's second
// barrier (vmcnt(0) drain of just-issued loads); now the stage for tile
// t+1 hides under tile t's 32 MFMA + 16 ds_read. 128x128 tile, BK=64,
// 4 waves (2x2), 16x16x32 bf16 MFMA. LDS XOR chunk-swizzle unchanged
// (bank conflicts measured 0): chunk c of row stored at slot c^(row&7);
// global source pre-permuted per lane (same 128B row span -> coalesced;
// lds-dma dest stays base+lane*16, linear as required).
template <bool OUT_BF16>
__global__ __launch_bounds__(256) void k_gemm_bt(
    const unsigned short* __restrict__ A,
    const unsigned short* __restrict__ Bw,
    const float* __restrict__ bias,
    void* __restrict__ Cout,
    int M, int Nn, int K)
{
  __shared__ unsigned short As[2][128 * 64];   // 16 KB per buf
  __shared__ unsigned short Bs[2][128 * 64];
  const int tid = threadIdx.x, lane = tid & 63;
  const int wv = tid >> 6, wr = wv >> 1, wc = wv & 1;
  const int q4 = lane >> 4, r = lane & 15;
  const long bm = (long)blockIdx.x * 128, bn = (long)blockIdx.y * 128;

  f32x4 acc[4][4] = {};

  int srow[4], sco[4];
#pragma unroll
  for (int j = 0; j < 4; ++j) {
    const int s = j * 256 + tid;
    srow[j] = s >> 3;
    sco[j] = ((s & 7) ^ (srow[j] & 7)) * 16;  // byte offset within row
  }

  auto stage = [&](int k0, int buf) {
#pragma unroll
    for (int j = 0; j < 4; ++j) {
      const int ldsoff = j * 4096 + tid * 16;
      async_ld16((char*)As[buf] + ldsoff,
                 (const char*)(A + (bm + srow[j]) * (long)K + k0) + sco[j]);
      async_ld16((char*)Bs[buf] + ldsoff,
                 (const char*)(Bw + (bn + srow[j]) * (long)K + k0) + sco[j]);
    }
  };

  stage(0, 0);  // prologue prefetch

  const int NT = K >> 6;
  for (int t = 0; t < NT; ++t) {
    const int cur = t & 1;
    // barrier drains this wave's lds-dma (stage(t), issued one full compute
    // phase ago) and guarantees all waves finished reading buf cur^1.
    __syncthreads();
    if (t + 1 < NT) stage((t + 1) * 64, cur ^ 1);

    const unsigned short* Ac = As[cur];
    const unsigned short* Bc = Bs[cur];

#pragma unroll
    for (int ks = 0; ks < 2; ++ks) {
      bf16x8 af[4], bfr[4];
#pragma unroll
      for (int i = 0; i < 4; ++i) {
        const int row = wr * 64 + i * 16 + r;
        const int ch = (ks * 4 + q4) ^ (row & 7);
        af[i] = *(const bf16x8*)(Ac + row * 64 + ch * 8);
      }
#pragma unroll
      for (int j = 0; j < 4; ++j) {
        const int row = wc * 64 + j * 16 + r;
        const int ch = (ks * 4 + q4) ^ (row & 7);
        bfr[j] = *(const bf16x8*)(Bc + row * 64 + ch * 8);
      }
#pragma unroll
      for (int i = 0; i < 4; ++i)
#pragma unroll
        for (int j = 0; j < 4; ++j)
          acc[i][j] = __builtin_amdgcn_mfma_f32_16x16x32_bf16(af[i], bfr[j], acc[i][j], 0, 0, 0);
    }
  }

#pragma unroll
  for (int j = 0; j < 4; ++j) {
    const long col = bn + wc * 64 + j * 16 + r;
    const float bv = bias[col];
#pragma unroll
    for (int i = 0; i < 4; ++i) {
#pragma unroll
      for (int rr = 0; rr < 4; ++rr) {
        const long rowg = bm + wr * 64 + i * 16 + q4 * 4 + rr;
        const float v = acc[i][j][rr] + bv;
        if (OUT_BF16)
          ((unsigned short*)Cout)[rowg * Nn + col] = f2bf(v);
        else
          ((float*)Cout)[rowg * Nn + col] = v;
      }
    }
  }
}

// ---------- transpose V: qkv[b,n,2C + h*64 + d] -> vt[(bh*64+d)*1024 + n] ----------
__global__ __launch_bounds__(256) void k_transpose_v(const unsigned short* __restrict__ qkv,
                                                     unsigned short* __restrict__ vt) {
  __shared__ unsigned short T[64][72];
  const int tid = threadIdx.x;
  const int bh = blockIdx.y, b = bh / 12, h = bh % 12;
  const int n0 = blockIdx.x * 64;
#pragma unroll
  for (int i = 0; i < 2; ++i) {
    int c = tid + i * 256, row = c >> 3, ch = c & 7;
    uint4 v = *(const uint4*)(qkv + ((long)(b * 1024 + n0 + row)) * 2304 + 1536 + h * 64 + ch * 8);
    *(uint4*)(&T[row][ch * 8]) = v;
  }
  __syncthreads();
#pragma unroll
  for (int i = 0; i < 2; ++i) {
    int c = tid + i * 256, d = c >> 3, ch = c & 7;
    unsigned short tmp[8];
#pragma unroll
    for (int j = 0; j < 8; ++j) tmp[j] = T[ch * 8 + j][d];
    *(uint4*)(vt + ((long)bh * 64 + d) * 1024 + n0 + ch * 8) = *(const uint4*)tmp;
  }
}

// ---------- flash attention (v3: async double-buffered K/V staging) ----------
__global__ __launch_bounds__(256) void k_flash(
    const unsigned short* __restrict__ qkv,  // [8192, 2304]
    const unsigned short* __restrict__ vt,   // [96*64, 1024]
    unsigned short* __restrict__ outp)       // [8192, 768]
{
  constexpr int LDP = 72;                     // Ps keeps +pad (reg-written)
  __shared__ unsigned short Ks[2][64 * 64];   // 8 KB per buf, linear swizzled
  __shared__ unsigned short Vts[2][64 * 64];
  __shared__ unsigned short Ps[4 * 32 * LDP];

  const int tid = threadIdx.x, lane = tid & 63;
  const int wv = tid >> 6, q4 = lane >> 4, r = lane & 15;
  const int bh = blockIdx.y, b = bh / 12, h = bh % 12;
  const int q0 = blockIdx.x * 128;
  const long qrow0 = (long)b * 1024;

  // swizzled staging offsets: slot s = i*256+tid, row = s>>3, chunk = (s&7)^(row&7)
  int srow[2], sco[2];
#pragma unroll
  for (int i = 0; i < 2; ++i) {
    const int s = i * 256 + tid;
    srow[i] = s >> 3;
    sco[i] = ((s & 7) ^ (srow[i] & 7)) * 8;   // element offset within 64-elem row
  }

  const unsigned short* Kg = qkv + qrow0 * 2304 + 768 + (long)h * 64;  // K rows
  const unsigned short* Vg = vt + (long)bh * 64 * 1024;                // V^T rows

  // Q fragments (held in regs for whole kernel)
  bf16x8 aq[2][2];
#pragma unroll
  for (int i = 0; i < 2; ++i)
#pragma unroll
    for (int kc = 0; kc < 2; ++kc)
      aq[i][kc] = *(const bf16x8*)(qkv + (qrow0 + q0 + wv * 32 + i * 16 + r) * 2304 + h * 64 + kc * 32 + q4 * 8);

  f32x4 o[2][4] = {};
  f32x4 lsum[2] = {};
  const bf16x8 ones = {0x3F80, 0x3F80, 0x3F80, 0x3F80, 0x3F80, 0x3F80, 0x3F80, 0x3F80};

  // stage tile (n0 = kv row offset) into buffer `buf`
  auto stage = [&](int n0, int buf) {
#pragma unroll
    for (int i = 0; i < 2; ++i) {
      const int ldsoff = (i * 256 + tid) * 16;  // linear dest: base + lane*16
      async_ld16((char*)Ks[buf] + ldsoff,
                 (const void*)(Kg + (long)(n0 + srow[i]) * 2304 + sco[i]));
      async_ld16((char*)Vts[buf] + ldsoff,
                 (const void*)(Vg + (long)srow[i] * 1024 + n0 + sco[i]));
    }
  };

  stage(0, 0);  // prologue prefetch

  for (int kt = 0; kt < 16; ++kt) {
    const int cur = kt & 1;
    __syncthreads();
    if (kt < 15) stage((kt + 1) * 64, cur ^ 1);

    const unsigned short* Kc = Ks[cur];
    const unsigned short* Vc = Vts[cur];

    // ---- QK^T ----
    f32x4 s[2][4] = {};
    {
      bf16x8 bk[4][2];
#pragma unroll
      for (int j = 0; j < 4; ++j)
#pragma unroll
        for (int kc = 0; kc < 2; ++kc) {
          const int row = j * 16 + r;
          const int ch = (kc * 4 + q4) ^ (row & 7);
          bk[j][kc] = *(const bf16x8*)(Kc + row * 64 + ch * 8);
        }
#pragma unroll
      for (int i = 0; i < 2; ++i)
#pragma unroll
        for (int j = 0; j < 4; ++j) {
          s[i][j] = __builtin_amdgcn_mfma_f32_16x16x32_bf16(aq[i][0], bk[j][0], s[i][j], 0, 0, 0);
          s[i][j] = __builtin_amdgcn_mfma_f32_16x16x32_bf16(aq[i][1], bk[j][1], s[i][j], 0, 0, 0);
        }
    }

    // ---- softmax (fixed-shift exp; normalization deferred to epilogue) ----
#pragma unroll
    for (int i = 0; i < 2; ++i)
#pragma unroll
      for (int j = 0; j < 4; ++j)
#pragma unroll
        for (int rr = 0; rr < 4; ++rr) {
          float p = __expf(fmaf(s[i][j][rr], 0.125f, -2.0f));
          Ps[(wv * 32 + i * 16 + q4 * 4 + rr) * LDP + j * 16 + r] = f2bf(p);
        }

    // ---- PV (+ row-sum via ones-MFMA) ----
    {
      bf16x8 bv[4][2];
#pragma unroll
      for (int jd = 0; jd < 4; ++jd)
#pragma unroll
        for (int kc = 0; kc < 2; ++kc) {
          const int row = jd * 16 + r;
          const int ch = (kc * 4 + q4) ^ (row & 7);
          bv[jd][kc] = *(const bf16x8*)(Vc + row * 64 + ch * 8);
        }
#pragma unroll
      for (int i = 0; i < 2; ++i) {
        bf16x8 ap0 = *(const bf16x8*)(Ps + (wv * 32 + i * 16 + r) * LDP + 0 + q4 * 8);
        bf16x8 ap1 = *(const bf16x8*)(Ps + (wv * 32 + i * 16 + r) * LDP + 32 + q4 * 8);
        lsum[i] = __builtin_amdgcn_mfma_f32_16x16x32_bf16(ap0, ones, lsum[i], 0, 0, 0);
        lsum[i] = __builtin_amdgcn_mfma_f32_16x16x32_bf16(ap1, ones, lsum[i], 0, 0, 0);
#pragma unroll
        for (int jd = 0; jd < 4; ++jd) {
          o[i][jd] = __builtin_amdgcn_mfma_f32_16x16x32_bf16(ap0, bv[jd][0], o[i][jd], 0, 0, 0);
          o[i][jd] = __builtin_amdgcn_mfma_f32_16x16x32_bf16(ap1, bv[jd][1], o[i][jd], 0, 0, 0);
        }
      }
    }
  }

#pragma unroll
  for (int i = 0; i < 2; ++i)
#pragma unroll
    for (int rr = 0; rr < 4; ++rr) {
      const float inv = 1.0f / lsum[i][rr];
      const long rowg = qrow0 + q0 + wv * 32 + i * 16 + q4 * 4 + rr;
#pragma unroll
      for (int jd = 0; jd < 4; ++jd)
        outp[rowg * 768 + h * 64 + jd * 16 + r] = f2bf(o[i][jd][rr] * inv);
    }
}

// ---------- launcher ----------
extern "C" void kernel_launch(void* const* d_in, const int* in_sizes, int n_in,
                              void* d_out, int out_size, void* d_ws, size_t ws_size,
                              hipStream_t stream) {
  const float* x      = (const float*)d_in[0];
  const float* qkv_w  = (const float*)d_in[1];
  const float* qkv_b  = (const float*)d_in[2];
  const float* proj_w = (const float*)d_in[3];
  const float* proj_b = (const float*)d_in[4];
  const float* mask   = (const float*)d_in[5];
  const float* mask_p = (const float*)d_in[6];

  char* ws = (char*)d_ws;
  unsigned short* qkv   = (unsigned short*)(ws);              // 8192*2304*2
  unsigned short* vt    = (unsigned short*)(ws + 37748736);   // 96*64*1024*2
  unsigned short* xbf   = (unsigned short*)(ws + 50331648);   // 8192*768*2 (reused as attn out)
  unsigned short* wqkv  = (unsigned short*)(ws + 62914560);   // 2304*768*2
  unsigned short* wproj = (unsigned short*)(ws + 66453504);   // 768*768*2

  k_prep<<<8448, 256, 0, stream>>>(x, xbf, qkv_w, mask, wqkv, proj_w, mask_p, wproj);
  k_gemm_bt<true><<<dim3(64, 18), 256, 0, stream>>>(xbf, wqkv, qkv_b, qkv, 8192, 2304, 768);
  k_transpose_v<<<dim3(16, 96), 256, 0, stream>>>(qkv, vt);
  k_flash<<<dim3(8, 96), 256, 0, stream>>>(qkv, vt, xbf);
  k_gemm_bt<false><<<dim3(64, 6), 256, 0, stream>>>(xbf, wproj, proj_b, d_out, 8192, 768, 768);
}

// Round 3
// 204.228 us; speedup vs baseline: 1.1020x; 1.0249x over previous
//
#include <hip/hip_runtime.h>
#include <hip/hip_bf16.h>

// ---------- types ----------
typedef short bf16x8 __attribute__((ext_vector_type(8)));
typedef float f32x4 __attribute__((ext_vector_type(4)));

typedef __attribute__((address_space(3))) unsigned int lds_u32;
typedef __attribute__((address_space(1))) const unsigned int gbl_cu32;

__device__ __forceinline__ void async_ld16(void* lds, const void* g) {
  __builtin_amdgcn_global_load_lds((gbl_cu32*)g, (lds_u32*)lds, 16, 0, 0);
}

__device__ __forceinline__ unsigned short f2bf(float f) {
  unsigned u = __builtin_bit_cast(unsigned, f);
  u += 0x7FFFu + ((u >> 16) & 1u);   // RNE; inputs finite
  return (unsigned short)(u >> 16);
}

// ---------- prep (merged): x->bf16, mask(qkv_w), mask(proj_w) ----------
__global__ void k_prep(const float* __restrict__ x, unsigned short* __restrict__ xo,
                       const float* __restrict__ w1, const float* __restrict__ m1,
                       unsigned short* __restrict__ o1,
                       const float* __restrict__ w2, const float* __restrict__ m2,
                       unsigned short* __restrict__ o2) {
  int blk = blockIdx.x;
  if (blk < 6144) {
    int i = blk * 256 + threadIdx.x;
    float4 v = ((const float4*)x)[i];
    ushort4 r;
    r.x = f2bf(v.x); r.y = f2bf(v.y); r.z = f2bf(v.z); r.w = f2bf(v.w);
    ((ushort4*)xo)[i] = r;
  } else if (blk < 6144 + 1728) {
    int i = (blk - 6144) * 256 + threadIdx.x;
    float4 wv = ((const float4*)w1)[i];
    float4 mv = ((const float4*)m1)[i];
    ushort4 r;
    r.x = f2bf(mv.x >= 0.005f ? wv.x : 0.0f);
    r.y = f2bf(mv.y >= 0.005f ? wv.y : 0.0f);
    r.z = f2bf(mv.z >= 0.005f ? wv.z : 0.0f);
    r.w = f2bf(mv.w >= 0.005f ? wv.w : 0.0f);
    ((ushort4*)o1)[i] = r;
  } else {
    int i = (blk - 6144 - 1728) * 256 + threadIdx.x;
    float4 wv = ((const float4*)w2)[i];
    float4 mv = ((const float4*)m2)[i];
    ushort4 r;
    r.x = f2bf(mv.x >= 0.005f ? wv.x : 0.0f);
    r.y = f2bf(mv.y >= 0.005f ? wv.y : 0.0f);
    r.z = f2bf(mv.z >= 0.005f ? wv.z : 0.0f);
    r.w = f2bf(mv.w >= 0.005f ? wv.w : 0.0f);
    ((ushort4*)o2)[i] = r;
  }
}

// ---------- GEMM: C[M,N] = A[M,K] * B[N,K]^T + bias[N] ----------
// dbuf + one barrier per K-step (unchanged this round). A-panel sharing is
// already XCD-local (blocks sharing bm are 64 apart, 64%8==0); B fits L2.
template <bool OUT_BF16>
__global__ __launch_bounds__(256) void k_gemm_bt(
    const unsigned short* __restrict__ A,
    const unsigned short* __restrict__ Bw,
    const float* __restrict__ bias,
    void* __restrict__ Cout,
    int M, int Nn, int K)
{
  __shared__ unsigned short As[2][128 * 64];   // 16 KB per buf
  __shared__ unsigned short Bs[2][128 * 64];
  const int tid = threadIdx.x, lane = tid & 63;
  const int wv = tid >> 6, wr = wv >> 1, wc = wv & 1;
  const int q4 = lane >> 4, r = lane & 15;
  const long bm = (long)blockIdx.x * 128, bn = (long)blockIdx.y * 128;

  f32x4 acc[4][4] = {};

  int srow[4], sco[4];
#pragma unroll
  for (int j = 0; j < 4; ++j) {
    const int s = j * 256 + tid;
    srow[j] = s >> 3;
    sco[j] = ((s & 7) ^ (srow[j] & 7)) * 16;  // byte offset within row
  }

  auto stage = [&](int k0, int buf) {
#pragma unroll
    for (int j = 0; j < 4; ++j) {
      const int ldsoff = j * 4096 + tid * 16;
      async_ld16((char*)As[buf] + ldsoff,
                 (const char*)(A + (bm + srow[j]) * (long)K + k0) + sco[j]);
      async_ld16((char*)Bs[buf] + ldsoff,
                 (const char*)(Bw + (bn + srow[j]) * (long)K + k0) + sco[j]);
    }
  };

  stage(0, 0);  // prologue prefetch

  const int NT = K >> 6;
  for (int t = 0; t < NT; ++t) {
    const int cur = t & 1;
    __syncthreads();
    if (t + 1 < NT) stage((t + 1) * 64, cur ^ 1);

    const unsigned short* Ac = As[cur];
    const unsigned short* Bc = Bs[cur];

#pragma unroll
    for (int ks = 0; ks < 2; ++ks) {
      bf16x8 af[4], bfr[4];
#pragma unroll
      for (int i = 0; i < 4; ++i) {
        const int row = wr * 64 + i * 16 + r;
        const int ch = (ks * 4 + q4) ^ (row & 7);
        af[i] = *(const bf16x8*)(Ac + row * 64 + ch * 8);
      }
#pragma unroll
      for (int j = 0; j < 4; ++j) {
        const int row = wc * 64 + j * 16 + r;
        const int ch = (ks * 4 + q4) ^ (row & 7);
        bfr[j] = *(const bf16x8*)(Bc + row * 64 + ch * 8);
      }
#pragma unroll
      for (int i = 0; i < 4; ++i)
#pragma unroll
        for (int j = 0; j < 4; ++j)
          acc[i][j] = __builtin_amdgcn_mfma_f32_16x16x32_bf16(af[i], bfr[j], acc[i][j], 0, 0, 0);
    }
  }

#pragma unroll
  for (int j = 0; j < 4; ++j) {
    const long col = bn + wc * 64 + j * 16 + r;
    const float bv = bias[col];
#pragma unroll
    for (int i = 0; i < 4; ++i) {
#pragma unroll
      for (int rr = 0; rr < 4; ++rr) {
        const long rowg = bm + wr * 64 + i * 16 + q4 * 4 + rr;
        const float v = acc[i][j][rr] + bv;
        if (OUT_BF16)
          ((unsigned short*)Cout)[rowg * Nn + col] = f2bf(v);
        else
          ((float*)Cout)[rowg * Nn + col] = v;
      }
    }
  }
}

// ---------- transpose V: qkv[b,n,2C + h*64 + d] -> vt[(bh*64+d)*1024 + n] ----------
__global__ __launch_bounds__(256) void k_transpose_v(const unsigned short* __restrict__ qkv,
                                                     unsigned short* __restrict__ vt) {
  __shared__ unsigned short T[64][72];
  const int tid = threadIdx.x;
  const int bh = blockIdx.y, b = bh / 12, h = bh % 12;
  const int n0 = blockIdx.x * 64;
#pragma unroll
  for (int i = 0; i < 2; ++i) {
    int c = tid + i * 256, row = c >> 3, ch = c & 7;
    uint4 v = *(const uint4*)(qkv + ((long)(b * 1024 + n0 + row)) * 2304 + 1536 + h * 64 + ch * 8);
    *(uint4*)(&T[row][ch * 8]) = v;
  }
  __syncthreads();
#pragma unroll
  for (int i = 0; i < 2; ++i) {
    int c = tid + i * 256, d = c >> 3, ch = c & 7;
    unsigned short tmp[8];
#pragma unroll
    for (int j = 0; j < 8; ++j) tmp[j] = T[ch * 8 + j][d];
    *(uint4*)(vt + ((long)bh * 64 + d) * 1024 + n0 + ch * 8) = *(const uint4*)tmp;
  }
}

// ---------- flash attention (v4: XCD-grouped block remap + exp2 fold) ----------
// v3's dbuf pipeline stalls because the 8 q-blocks sharing one (b,h)'s K/V
// panel got consecutive linear ids -> round-robin across 8 XCDs -> every
// XCD refetches K/V from HBM (FETCH 104.5 MB vs 37 MB unique; stage loads
// ~900cyc HBM misses that one compute phase can't cover). Bijective remap:
// n = y*8+x ; bh = (n&7)*12 + (n>>6) ; q0 = ((n>>3)&7)*128.
// Same bh => same n%8 => same XCD (round-robin assumption; if mapping
// differs it's a harmless permutation). 12 groups x 256 KB = 3 MB K/V per
// XCD L2 (4 MB) -> stage becomes L2-hit, hidden under compute.
__global__ __launch_bounds__(256) void k_flash(
    const unsigned short* __restrict__ qkv,  // [8192, 2304]
    const unsigned short* __restrict__ vt,   // [96*64, 1024]
    unsigned short* __restrict__ outp)       // [8192, 768]
{
  constexpr int LDP = 72;                     // Ps keeps +pad (reg-written)
  __shared__ unsigned short Ks[2][64 * 64];   // 8 KB per buf, linear swizzled
  __shared__ unsigned short Vts[2][64 * 64];
  __shared__ unsigned short Ps[4 * 32 * LDP];

  const int tid = threadIdx.x, lane = tid & 63;
  const int wv = tid >> 6, q4 = lane >> 4, r = lane & 15;

  // XCD-grouping remap (bijective over 768)
  const int nlin = blockIdx.y * 8 + blockIdx.x;
  const int bh = (nlin & 7) * 12 + (nlin >> 6);   // 0..95
  const int q0 = ((nlin >> 3) & 7) * 128;
  const int b = bh / 12, h = bh % 12;
  const long qrow0 = (long)b * 1024;

  // swizzled staging offsets: slot s = i*256+tid, row = s>>3, chunk = (s&7)^(row&7)
  int srow[2], sco[2];
#pragma unroll
  for (int i = 0; i < 2; ++i) {
    const int s = i * 256 + tid;
    srow[i] = s >> 3;
    sco[i] = ((s & 7) ^ (srow[i] & 7)) * 8;   // element offset within 64-elem row
  }

  const unsigned short* Kg = qkv + qrow0 * 2304 + 768 + (long)h * 64;  // K rows
  const unsigned short* Vg = vt + (long)bh * 64 * 1024;                // V^T rows

  // Q fragments (held in regs for whole kernel)
  bf16x8 aq[2][2];
#pragma unroll
  for (int i = 0; i < 2; ++i)
#pragma unroll
    for (int kc = 0; kc < 2; ++kc)
      aq[i][kc] = *(const bf16x8*)(qkv + (qrow0 + q0 + wv * 32 + i * 16 + r) * 2304 + h * 64 + kc * 32 + q4 * 8);

  f32x4 o[2][4] = {};
  f32x4 lsum[2] = {};
  const bf16x8 ones = {0x3F80, 0x3F80, 0x3F80, 0x3F80, 0x3F80, 0x3F80, 0x3F80, 0x3F80};

  // stage tile (n0 = kv row offset) into buffer `buf`
  auto stage = [&](int n0, int buf) {
#pragma unroll
    for (int i = 0; i < 2; ++i) {
      const int ldsoff = (i * 256 + tid) * 16;  // linear dest: base + lane*16
      async_ld16((char*)Ks[buf] + ldsoff,
                 (const void*)(Kg + (long)(n0 + srow[i]) * 2304 + sco[i]));
      async_ld16((char*)Vts[buf] + ldsoff,
                 (const void*)(Vg + (long)srow[i] * 1024 + n0 + sco[i]));
    }
  };

  stage(0, 0);  // prologue prefetch

  for (int kt = 0; kt < 16; ++kt) {
    const int cur = kt & 1;
    __syncthreads();
    if (kt < 15) stage((kt + 1) * 64, cur ^ 1);

    const unsigned short* Kc = Ks[cur];
    const unsigned short* Vc = Vts[cur];

    // ---- QK^T ----
    f32x4 s[2][4] = {};
    {
      bf16x8 bk[4][2];
#pragma unroll
      for (int j = 0; j < 4; ++j)
#pragma unroll
        for (int kc = 0; kc < 2; ++kc) {
          const int row = j * 16 + r;
          const int ch = (kc * 4 + q4) ^ (row & 7);
          bk[j][kc] = *(const bf16x8*)(Kc + row * 64 + ch * 8);
        }
#pragma unroll
      for (int i = 0; i < 2; ++i)
#pragma unroll
        for (int j = 0; j < 4; ++j) {
          s[i][j] = __builtin_amdgcn_mfma_f32_16x16x32_bf16(aq[i][0], bk[j][0], s[i][j], 0, 0, 0);
          s[i][j] = __builtin_amdgcn_mfma_f32_16x16x32_bf16(aq[i][1], bk[j][1], s[i][j], 0, 0, 0);
        }
    }

    // ---- softmax: p = exp(0.125*s - 2) = exp2(s*0.125*log2e - 2*log2e) ----
#pragma unroll
    for (int i = 0; i < 2; ++i)
#pragma unroll
      for (int j = 0; j < 4; ++j)
#pragma unroll
        for (int rr = 0; rr < 4; ++rr) {
          float p = __builtin_amdgcn_exp2f(fmaf(s[i][j][rr], 0.18033688f, -2.88539008f));
          Ps[(wv * 32 + i * 16 + q4 * 4 + rr) * LDP + j * 16 + r] = f2bf(p);
        }

    // ---- PV (+ row-sum via ones-MFMA) ----
    {
      bf16x8 bv[4][2];
#pragma unroll
      for (int jd = 0; jd < 4; ++jd)
#pragma unroll
        for (int kc = 0; kc < 2; ++kc) {
          const int row = jd * 16 + r;
          const int ch = (kc * 4 + q4) ^ (row & 7);
          bv[jd][kc] = *(const bf16x8*)(Vc + row * 64 + ch * 8);
        }
#pragma unroll
      for (int i = 0; i < 2; ++i) {
        bf16x8 ap0 = *(const bf16x8*)(Ps + (wv * 32 + i * 16 + r) * LDP + 0 + q4 * 8);
        bf16x8 ap1 = *(const bf16x8*)(Ps + (wv * 32 + i * 16 + r) * LDP + 32 + q4 * 8);
        lsum[i] = __builtin_amdgcn_mfma_f32_16x16x32_bf16(ap0, ones, lsum[i], 0, 0, 0);
        lsum[i] = __builtin_amdgcn_mfma_f32_16x16x32_bf16(ap1, ones, lsum[i], 0, 0, 0);
#pragma unroll
        for (int jd = 0; jd < 4; ++jd) {
          o[i][jd] = __builtin_amdgcn_mfma_f32_16x16x32_bf16(ap0, bv[jd][0], o[i][jd], 0, 0, 0);
          o[i][jd] = __builtin_amdgcn_mfma_f32_16x16x32_bf16(ap1, bv[jd][1], o[i][jd], 0, 0, 0);
        }
      }
    }
  }

#pragma unroll
  for (int i = 0; i < 2; ++i)
#pragma unroll
    for (int rr = 0; rr < 4; ++rr) {
      const float inv = 1.0f / lsum[i][rr];
      const long rowg = qrow0 + q0 + wv * 32 + i * 16 + q4 * 4 + rr;
#pragma unroll
      for (int jd = 0; jd < 4; ++jd)
        outp[rowg * 768 + h * 64 + jd * 16 + r] = f2bf(o[i][jd][rr] * inv);
    }
}

// ---------- launcher ----------
extern "C" void kernel_launch(void* const* d_in, const int* in_sizes, int n_in,
                              void* d_out, int out_size, void* d_ws, size_t ws_size,
                              hipStream_t stream) {
  const float* x      = (const float*)d_in[0];
  const float* qkv_w  = (const float*)d_in[1];
  const float* qkv_b  = (const float*)d_in[2];
  const float* proj_w = (const float*)d_in[3];
  const float* proj_b = (const float*)d_in[4];
  const float* mask   = (const float*)d_in[5];
  const float* mask_p = (const float*)d_in[6];

  char* ws = (char*)d_ws;
  unsigned short* qkv   = (unsigned short*)(ws);              // 8192*2304*2
  unsigned short* vt    = (unsigned short*)(ws + 37748736);   // 96*64*1024*2
  unsigned short* xbf   = (unsigned short*)(ws + 50331648);   // 8192*768*2 (reused as attn out)
  unsigned short* wqkv  = (unsigned short*)(ws + 62914560);   // 2304*768*2
  unsigned short* wproj = (unsigned short*)(ws + 66453504);   // 768*768*2

  k_prep<<<8448, 256, 0, stream>>>(x, xbf, qkv_w, mask, wqkv, proj_w, mask_p, wproj);
  k_gemm_bt<true><<<dim3(64, 18), 256, 0, stream>>>(xbf, wqkv, qkv_b, qkv, 8192, 2304, 768);
  k_transpose_v<<<dim3(16, 96), 256, 0, stream>>>(qkv, vt);
  k_flash<<<dim3(8, 96), 256, 0, stream>>>(qkv, vt, xbf);
  k_gemm_bt<false><<<dim3(64, 6), 256, 0, stream>>>(xbf, wproj, proj_b, d_out, 8192, 768, 768);
}